// Round 1
// baseline (101.231 us; speedup 1.0000x reference)
//
#include <hip/hip_runtime.h>

#define BB 32
#define TT 2048
#define HH 1024
#define KK 11
#define PD 5

// ---------------- Kernel 1: pax[b,t] = dot(eh[b,t,:], dhx[b,:]) ----------------
// one wave per (b,t) row; 4 rows per 256-thread block; dhx staged in LDS.
__global__ __launch_bounds__(256) void pax_kernel(const float* __restrict__ eh,
                                                  const float* __restrict__ dhx,
                                                  float* __restrict__ pax) {
    __shared__ float4 dsh[HH / 4];
    const int b  = blockIdx.x >> 9;            // 512 blocks per batch (T/4)
    const int t0 = (blockIdx.x & 511) << 2;    // 4 rows per block
    const int tid = threadIdx.x;

    dsh[tid] = reinterpret_cast<const float4*>(dhx + (size_t)b * HH)[tid];
    __syncthreads();

    const int wave = tid >> 6;
    const int lane = tid & 63;
    const int t = t0 + wave;
    const float4* e4 = reinterpret_cast<const float4*>(eh) + ((size_t)b * TT + t) * (HH / 4);

    float acc = 0.f;
#pragma unroll
    for (int i = 0; i < 4; ++i) {
        float4 e = e4[i * 64 + lane];
        float4 d = dsh[i * 64 + lane];
        acc += e.x * d.x + e.y * d.y + e.z * d.z + e.w * d.w;
    }
#pragma unroll
    for (int off = 32; off > 0; off >>= 1)
        acc += __shfl_down(acc, off, 64);
    if (lane == 0) pax[(size_t)b * TT + t] = acc;
}

// ---------------- Kernel 2: loc conv + softmax over T, one block per b ----------
__global__ __launch_bounds__(256) void softmax_kernel(const float* __restrict__ pax,
                                                      const float* __restrict__ ax,
                                                      const float* __restrict__ conv_w,
                                                      const float* __restrict__ conv_b,
                                                      float* __restrict__ ax_new) {
    const int b = blockIdx.x;
    const int tid = threadIdx.x;
    __shared__ float axs[TT + 2 * PD];
    __shared__ float wsh[KK];
    __shared__ float red[4];

    if (tid < KK) wsh[tid] = conv_w[tid];
    for (int i = tid; i < TT + 2 * PD; i += 256) {
        int t = i - PD;
        axs[i] = (t >= 0 && t < TT) ? ax[(size_t)b * TT + t] : 0.f;
    }
    __syncthreads();

    const float cb = conv_b[0];
    float s[8];
    float m = -INFINITY;
#pragma unroll
    for (int j = 0; j < 8; ++j) {
        int t = j * 256 + tid;
        float loc = cb;
#pragma unroll
        for (int k = 0; k < KK; ++k) loc += axs[t + k] * wsh[k];
        float v = pax[(size_t)b * TT + t] + loc;
        s[j] = v;
        m = fmaxf(m, v);
    }
    // block max reduce
#pragma unroll
    for (int off = 32; off > 0; off >>= 1) m = fmaxf(m, __shfl_xor(m, off, 64));
    if ((tid & 63) == 0) red[tid >> 6] = m;
    __syncthreads();
    m = fmaxf(fmaxf(red[0], red[1]), fmaxf(red[2], red[3]));

    float e[8];
    float sum = 0.f;
#pragma unroll
    for (int j = 0; j < 8; ++j) { e[j] = __expf(s[j] - m); sum += e[j]; }
#pragma unroll
    for (int off = 32; off > 0; off >>= 1) sum += __shfl_xor(sum, off, 64);
    __syncthreads();   // ensure everyone has read red[] (max) before overwrite
    if ((tid & 63) == 0) red[tid >> 6] = sum;
    __syncthreads();
    sum = red[0] + red[1] + red[2] + red[3];
    const float inv = 1.f / sum;
#pragma unroll
    for (int j = 0; j < 8; ++j)
        ax_new[(size_t)b * TT + j * 256 + tid] = e[j] * inv;
}

// ---------------- Kernel 3: partial sx over T-chunks -----------------------------
// grid (nchunk, B); each thread owns 4 h (float4); weights broadcast from LDS.
__global__ __launch_bounds__(256) void sx_partial_kernel(const float* __restrict__ eh,
                                                         const float* __restrict__ ax_new,
                                                         float* __restrict__ part) {
    const int c = blockIdx.x;
    const int b = blockIdx.y;
    const int nchunk = gridDim.x;
    const int tchunk = TT / nchunk;
    const int t0 = c * tchunk;
    const int tid = threadIdx.x;

    extern __shared__ float wsm[];
    for (int i = tid; i < tchunk; i += 256)
        wsm[i] = ax_new[(size_t)b * TT + t0 + i];
    __syncthreads();

    const float4* e4 = reinterpret_cast<const float4*>(eh) + ((size_t)b * TT + t0) * (HH / 4);
    float4 acc = {0.f, 0.f, 0.f, 0.f};
    for (int j = 0; j < tchunk; ++j) {
        float w = wsm[j];
        float4 e = e4[(size_t)j * (HH / 4) + tid];
        acc.x += w * e.x; acc.y += w * e.y; acc.z += w * e.z; acc.w += w * e.w;
    }
    reinterpret_cast<float4*>(part)[((size_t)b * nchunk + c) * (HH / 4) + tid] = acc;
}

// ---------------- Kernel 4: reduce partials -> sx -------------------------------
__global__ __launch_bounds__(256) void sx_reduce_kernel(const float* __restrict__ part,
                                                        float* __restrict__ sx,
                                                        int nchunk) {
    const int idx = blockIdx.x * 256 + threadIdx.x;   // b*H + h
    const int b = idx >> 10;
    const int h = idx & (HH - 1);
    float acc = 0.f;
    for (int c = 0; c < nchunk; ++c)
        acc += part[((size_t)b * nchunk + c) * HH + h];
    sx[idx] = acc;
}

extern "C" void kernel_launch(void* const* d_in, const int* in_sizes, int n_in,
                              void* d_out, int out_size, void* d_ws, size_t ws_size,
                              hipStream_t stream) {
    const float* eh  = (const float*)d_in[0];
    const float* dhx = (const float*)d_in[1];
    const float* ax  = (const float*)d_in[2];
    const float* cw  = (const float*)d_in[3];
    const float* cb  = (const float*)d_in[4];

    float* out    = (float*)d_out;
    float* sx     = out;               // (B,1,H) -> 32768 floats
    float* ax_new = out + BB * HH;     // (B,T)   -> 65536 floats

    float* pax  = (float*)d_ws;        // B*T floats
    float* part = pax + (size_t)BB * TT;

    // pick chunk count that fits the workspace: need (B*T + B*nc*H)*4 bytes
    int nc = 32;
    while (nc > 4 && ((size_t)BB * TT + (size_t)BB * nc * HH) * 4 > ws_size) nc >>= 1;

    pax_kernel<<<BB * TT / 4, 256, 0, stream>>>(eh, dhx, pax);
    softmax_kernel<<<BB, 256, 0, stream>>>(pax, ax, cw, cb, ax_new);
    dim3 g3(nc, BB);
    sx_partial_kernel<<<g3, 256, (TT / nc) * sizeof(float), stream>>>(eh, ax_new, part);
    sx_reduce_kernel<<<BB * HH / 256, 256, 0, stream>>>(part, sx, nc);
}

// Round 2
// 75.409 us; speedup vs baseline: 1.3424x; 1.3424x over previous
//
#include <hip/hip_runtime.h>

#define BB 32
#define TT 2048
#define HH 1024
#define KK 11
#define PD 5

// ---------------- Fused main kernel --------------------------------------------
// grid (NC, B): block owns chunk c of TC=T/NC timesteps for batch b.
// Reads eh ONCE: per 8-row batch, computes s_t = eh[t,:]·dhx + loc[t] via block
// reduce, then online-softmax accumulates P[h] = sum exp(s_t - m) * eh[t,h].
// Writes per-chunk (m, Z, P[.]) partials + stashes raw s_t for the ax_new pass.
__global__ __launch_bounds__(256) void fused_main_kernel(
    const float* __restrict__ eh, const float* __restrict__ dhx,
    const float* __restrict__ ax, const float* __restrict__ conv_w,
    const float* __restrict__ conv_b,
    float* __restrict__ stash, float* __restrict__ mArr,
    float* __restrict__ ZArr, float* __restrict__ part) {
    const int NC = gridDim.x;
    const int TC = TT / NC;
    const int c = blockIdx.x, b = blockIdx.y;
    const int t0 = c * TC;
    const int tid = threadIdx.x;
    const int wave = tid >> 6, lane = tid & 63;

    extern __shared__ float sm[];
    float* wsh    = sm;        // 16: conv weights
    float* red    = sm + 16;   // 32: 4 waves x 8 rows partials
    float* loc_sh = sm + 48;   // TC: conv output for this chunk

    if (tid < KK) wsh[tid] = conv_w[tid];
    __syncthreads();
    const float cb = conv_b[0];
    for (int i = tid; i < TC; i += 256) {
        float acc = cb;
#pragma unroll
        for (int k = 0; k < KK; ++k) {
            int t = t0 + i - PD + k;
            float a = (t >= 0 && t < TT) ? ax[(size_t)b * TT + t] : 0.f;
            acc += a * wsh[k];
        }
        loc_sh[i] = acc;
    }

    // each thread owns h = 4*tid..4*tid+3; dhx slice lives in registers
    const float4 dh = reinterpret_cast<const float4*>(dhx)[b * (HH / 4) + tid];
    const float4* e4 =
        reinterpret_cast<const float4*>(eh) + ((size_t)b * TT + t0) * (HH / 4);

    float m = -INFINITY, Z = 0.f;
    float4 P = {0.f, 0.f, 0.f, 0.f};
    __syncthreads();

    for (int tt = 0; tt < TC; tt += 8) {
        float4 ev[8];
        float s[8];
#pragma unroll
        for (int j = 0; j < 8; ++j) {
            ev[j] = e4[(size_t)(tt + j) * (HH / 4) + tid];
            s[j] = ev[j].x * dh.x + ev[j].y * dh.y + ev[j].z * dh.z + ev[j].w * dh.w;
        }
        // batched block reduce: 8 rows at once (amortizes the 2 syncs)
#pragma unroll
        for (int j = 0; j < 8; ++j)
#pragma unroll
            for (int off = 32; off > 0; off >>= 1)
                s[j] += __shfl_xor(s[j], off, 64);
        if (lane == 0) {
#pragma unroll
            for (int j = 0; j < 8; ++j) red[wave * 8 + j] = s[j];
        }
        __syncthreads();
#pragma unroll
        for (int j = 0; j < 8; ++j)
            s[j] = red[j] + red[8 + j] + red[16 + j] + red[24 + j] + loc_sh[tt + j];
        __syncthreads();  // red[] reused next batch

        // stash raw scores for the ax_new pass (static-index predicated stores)
#pragma unroll
        for (int j = 0; j < 8; ++j)
            if (tid == j) stash[(size_t)b * TT + t0 + tt + j] = s[j];

        float mb = s[0];
#pragma unroll
        for (int j = 1; j < 8; ++j) mb = fmaxf(mb, s[j]);
        if (mb > m) {  // block-uniform branch
            float sc = __expf(m - mb);
            Z *= sc;
            P.x *= sc; P.y *= sc; P.z *= sc; P.w *= sc;
            m = mb;
        }
#pragma unroll
        for (int j = 0; j < 8; ++j) {
            float p = __expf(s[j] - m);
            Z += p;
            P.x += p * ev[j].x; P.y += p * ev[j].y;
            P.z += p * ev[j].z; P.w += p * ev[j].w;
        }
    }

    reinterpret_cast<float4*>(part)[((size_t)b * NC + c) * (HH / 4) + tid] = P;
    if (tid == 0) {
        mArr[b * NC + c] = m;
        ZArr[b * NC + c] = Z;
    }
}

// ---------------- Combine chunk partials -> sx, stash (m_b, Z_b) ----------------
__global__ __launch_bounds__(256) void combine_kernel(
    const float* __restrict__ mArr, const float* __restrict__ ZArr,
    const float* __restrict__ part, float* __restrict__ sx,
    float* __restrict__ mZb, int NC) {
    const int b = blockIdx.y;
    const int h = blockIdx.x * 256 + threadIdx.x;

    float m = -INFINITY;
    for (int c = 0; c < NC; ++c) m = fmaxf(m, mArr[b * NC + c]);
    float Z = 0.f;
    for (int c = 0; c < NC; ++c) Z += __expf(mArr[b * NC + c] - m) * ZArr[b * NC + c];

    float acc = 0.f;
    for (int c = 0; c < NC; ++c)
        acc += __expf(mArr[b * NC + c] - m) * part[((size_t)b * NC + c) * HH + h];
    sx[(size_t)b * HH + h] = acc / Z;

    if (blockIdx.x == 0 && threadIdx.x == 0) {
        mZb[b * 2]     = m;
        mZb[b * 2 + 1] = Z;
    }
}

// ---------------- ax_new from stashed scores ------------------------------------
__global__ __launch_bounds__(256) void axnew_kernel(
    const float* __restrict__ stash, const float* __restrict__ mZb,
    float* __restrict__ ax_new) {
    const int idx = blockIdx.x * 256 + threadIdx.x;
    const int b = idx >> 11;  // T = 2048
    const float m = mZb[b * 2];
    const float invZ = 1.f / mZb[b * 2 + 1];
    ax_new[idx] = __expf(stash[idx] - m) * invZ;
}

extern "C" void kernel_launch(void* const* d_in, const int* in_sizes, int n_in,
                              void* d_out, int out_size, void* d_ws, size_t ws_size,
                              hipStream_t stream) {
    const float* eh  = (const float*)d_in[0];
    const float* dhx = (const float*)d_in[1];
    const float* ax  = (const float*)d_in[2];
    const float* cw  = (const float*)d_in[3];
    const float* cb  = (const float*)d_in[4];

    float* out    = (float*)d_out;
    float* sx     = out;            // (B,1,H)
    float* ax_new = out + BB * HH;  // (B,T)

    // pick chunk count that fits the workspace
    int nc = 64;
    while (nc > 8 &&
           ((size_t)BB * TT + 2ull * BB * nc + 2ull * BB + (size_t)BB * nc * HH + 64) * 4 >
               ws_size)
        nc >>= 1;

    float* stash = (float*)d_ws;                 // B*T
    float* mArr  = stash + (size_t)BB * TT;      // B*nc
    float* ZArr  = mArr + (size_t)BB * nc;       // B*nc
    float* mZb   = ZArr + (size_t)BB * nc;       // 2*B
    float* part  = mZb + 2 * BB;                 // B*nc*H (16B-aligned: offset mult of 4)

    const int TC = TT / nc;
    const size_t lds_bytes = (48 + TC) * sizeof(float);

    dim3 gmain(nc, BB);
    fused_main_kernel<<<gmain, 256, lds_bytes, stream>>>(eh, dhx, ax, cw, cb,
                                                         stash, mArr, ZArr, part);
    dim3 gcomb(HH / 256, BB);
    combine_kernel<<<gcomb, 256, 0, stream>>>(mArr, ZArr, part, sx, mZb, nc);
    axnew_kernel<<<BB * TT / 256, 256, 0, stream>>>(stash, mZb, ax_new);
}

// Round 3
// 61.149 us; speedup vs baseline: 1.6555x; 1.2332x over previous
//
#include <hip/hip_runtime.h>

#define BB 32
#define TT 2048
#define HH 1024
#define KK 11
#define PD 5

// ---------------- Fused main kernel --------------------------------------------
// grid (NC, B): block owns chunk c of TC=T/NC timesteps for batch b.
// Reads eh ONCE. Per 8-row batch: partial dots -> 10-shfl tree reduce
// (lane l&7 holds row sum) -> cross-wave via double-buffered LDS (1 barrier) ->
// online-softmax accumulate P[h].
__global__ __launch_bounds__(256) void fused_main_kernel(
    const float* __restrict__ eh, const float* __restrict__ dhx,
    const float* __restrict__ ax, const float* __restrict__ conv_w,
    const float* __restrict__ conv_b,
    float* __restrict__ stash, float* __restrict__ mArr,
    float* __restrict__ ZArr, float* __restrict__ part) {
    const int NC = gridDim.x;
    const int TC = TT / NC;
    const int c = blockIdx.x, b = blockIdx.y;
    const int t0 = c * TC;
    const int tid = threadIdx.x;
    const int wave = tid >> 6, lane = tid & 63;

    extern __shared__ float sm[];
    float* wsh    = sm;        // 16: conv weights
    float* red    = sm + 16;   // 2 x 32: double-buffered cross-wave partials
    float* loc_sh = sm + 80;   // TC: conv output for this chunk

    if (tid < KK) wsh[tid] = conv_w[tid];
    __syncthreads();
    const float cb = conv_b[0];
    for (int i = tid; i < TC; i += 256) {
        float acc = cb;
#pragma unroll
        for (int k = 0; k < KK; ++k) {
            int t = t0 + i - PD + k;
            float a = (t >= 0 && t < TT) ? ax[(size_t)b * TT + t] : 0.f;
            acc += a * wsh[k];
        }
        loc_sh[i] = acc;
    }
    // no barrier needed here: the first loop-iteration barrier covers loc_sh/red

    const float4 dh = reinterpret_cast<const float4*>(dhx)[b * (HH / 4) + tid];
    const float4* e4 =
        reinterpret_cast<const float4*>(eh) + ((size_t)b * TT + t0) * (HH / 4);

    float m = -INFINITY, Z = 0.f;
    float4 P = {0.f, 0.f, 0.f, 0.f};
    const int s0 = lane & 1, s1 = (lane >> 1) & 1, s2 = (lane >> 2) & 1;

    int ibuf = 0;
    for (int tt = 0; tt < TC; tt += 8, ibuf ^= 1) {
        float4 ev[8];
        float s[8];
#pragma unroll
        for (int j = 0; j < 8; ++j) {
            ev[j] = e4[(size_t)(tt + j) * (HH / 4) + tid];
            s[j] = ev[j].x * dh.x + ev[j].y * dh.y + ev[j].z * dh.z + ev[j].w * dh.w;
        }
        // ---- 10-shfl tree: 8 rows -> lane (l&7) holds full-wave row sum ----
        float u[4];
#pragma unroll
        for (int j = 0; j < 4; ++j) {
            float keep = s0 ? s[2 * j + 1] : s[2 * j];
            float send = s0 ? s[2 * j] : s[2 * j + 1];
            u[j] = keep + __shfl_xor(send, 1, 64);
        }
        float v[2];
#pragma unroll
        for (int j = 0; j < 2; ++j) {
            float keep = s1 ? u[2 * j + 1] : u[2 * j];
            float send = s1 ? u[2 * j] : u[2 * j + 1];
            v[j] = keep + __shfl_xor(send, 2, 64);
        }
        float w;
        {
            float keep = s2 ? v[1] : v[0];
            float send = s2 ? v[0] : v[1];
            w = keep + __shfl_xor(send, 4, 64);
            w += __shfl_xor(w, 8, 64);
            w += __shfl_xor(w, 16, 64);
            w += __shfl_xor(w, 32, 64);
        }
        if (lane < 8) red[ibuf * 32 + wave * 8 + lane] = w;
        __syncthreads();
        const float* rb = red + ibuf * 32;
        if (tid < 8) {
            float vf = rb[tid] + rb[8 + tid] + rb[16 + tid] + rb[24 + tid] +
                       loc_sh[tt + tid];
            stash[(size_t)b * TT + t0 + tt + tid] = vf;
        }
#pragma unroll
        for (int j = 0; j < 8; ++j)
            s[j] = rb[j] + rb[8 + j] + rb[16 + j] + rb[24 + j] + loc_sh[tt + j];

        float mb = s[0];
#pragma unroll
        for (int j = 1; j < 8; ++j) mb = fmaxf(mb, s[j]);
        if (mb > m) {  // block-uniform
            float sc = __expf(m - mb);
            Z *= sc;
            P.x *= sc; P.y *= sc; P.z *= sc; P.w *= sc;
            m = mb;
        }
#pragma unroll
        for (int j = 0; j < 8; ++j) {
            float p = __expf(s[j] - m);
            Z += p;
            P.x += p * ev[j].x; P.y += p * ev[j].y;
            P.z += p * ev[j].z; P.w += p * ev[j].w;
        }
        // next iter writes red[ibuf^1]; same-buffer reuse separated by barrier
    }

    reinterpret_cast<float4*>(part)[((size_t)b * NC + c) * (HH / 4) + tid] = P;
    if (tid == 0) {
        mArr[b * NC + c] = m;
        ZArr[b * NC + c] = Z;
    }
}

// ---------------- Merged tail: sx combine + ax_new ------------------------------
// grid (5, B): blockIdx.x<4 -> sx quarter; ==4 -> ax_new for batch b.
// Each block recomputes global (m, Z) from the tiny mArr/ZArr.
__global__ __launch_bounds__(256) void tail_kernel(
    const float* __restrict__ mArr, const float* __restrict__ ZArr,
    const float* __restrict__ part, const float* __restrict__ stash,
    float* __restrict__ sx, float* __restrict__ ax_new, int NC) {
    const int b = blockIdx.y;
    float mg = -INFINITY;
    for (int c = 0; c < NC; ++c) mg = fmaxf(mg, mArr[b * NC + c]);
    float Zg = 0.f;
    for (int c = 0; c < NC; ++c) Zg += __expf(mArr[b * NC + c] - mg) * ZArr[b * NC + c];

    if (blockIdx.x < 4) {
        const int h = blockIdx.x * 256 + threadIdx.x;
        float acc = 0.f;
        for (int c = 0; c < NC; ++c)
            acc += __expf(mArr[b * NC + c] - mg) * part[((size_t)b * NC + c) * HH + h];
        sx[(size_t)b * HH + h] = acc / Zg;
    } else {
        const float inv = 1.f / Zg;
        for (int j = 0; j < TT; j += 256) {
            int t = j + threadIdx.x;
            ax_new[(size_t)b * TT + t] =
                __expf(stash[(size_t)b * TT + t] - mg) * inv;
        }
    }
}

extern "C" void kernel_launch(void* const* d_in, const int* in_sizes, int n_in,
                              void* d_out, int out_size, void* d_ws, size_t ws_size,
                              hipStream_t stream) {
    const float* eh  = (const float*)d_in[0];
    const float* dhx = (const float*)d_in[1];
    const float* ax  = (const float*)d_in[2];
    const float* cw  = (const float*)d_in[3];
    const float* cb  = (const float*)d_in[4];

    float* out    = (float*)d_out;
    float* sx     = out;            // (B,1,H)
    float* ax_new = out + BB * HH;  // (B,T)

    int nc = 32;
    while (nc > 4 &&
           ((size_t)BB * TT + 2ull * BB * nc + (size_t)BB * nc * HH + 64) * 4 > ws_size)
        nc >>= 1;

    float* stash = (float*)d_ws;             // B*T
    float* mArr  = stash + (size_t)BB * TT;  // B*nc
    float* ZArr  = mArr + (size_t)BB * nc;   // B*nc
    float* part  = ZArr + (size_t)BB * nc;   // B*nc*H (float4-aligned)

    const int TC = TT / nc;
    const size_t lds_bytes = (80 + TC) * sizeof(float);

    dim3 gmain(nc, BB);
    fused_main_kernel<<<gmain, 256, lds_bytes, stream>>>(eh, dhx, ax, cw, cb,
                                                         stash, mArr, ZArr, part);
    dim3 gtail(5, BB);
    tail_kernel<<<gtail, 256, 0, stream>>>(mArr, ZArr, part, stash, sx, ax_new, nc);
}

// Round 4
// 60.577 us; speedup vs baseline: 1.6711x; 1.0095x over previous
//
#include <hip/hip_runtime.h>

#define BB 32
#define TT 2048
#define HH 1024
#define KK 11
#define PD 5

// ---------------- Fused main kernel --------------------------------------------
// grid (NC, B): block owns chunk c (TC = T/NC rows) of batch b.
// Each WAVE owns every 4th row: its 64 lanes x 4 float4 = full H row.
// Row dot = 16 lane FMAs + 6-shfl butterfly (all lanes get s). No barriers,
// no LDS in the main loop; per-wave online softmax; one LDS combine at end.
__global__ __launch_bounds__(256) void fused_main_kernel(
    const float* __restrict__ eh, const float* __restrict__ dhx,
    const float* __restrict__ ax, const float* __restrict__ conv_w,
    const float* __restrict__ conv_b,
    float* __restrict__ stash, float* __restrict__ mArr,
    float* __restrict__ ZArr, float* __restrict__ part) {
    const int NC = gridDim.x;
    const int TC = TT / NC;
    const int ROWS = TC / 4;  // rows per wave
    const int c = blockIdx.x, b = blockIdx.y;
    const int t0 = c * TC;
    const int tid = threadIdx.x;
    const int wave = tid >> 6, lane = tid & 63;

    extern __shared__ float sm[];
    float* wsh    = sm;        // 16: conv weights
    float* mz     = sm + 16;   // 8: per-wave m, Z
    float* loc_sh = sm + 24;   // TC: conv output (offset 24+TC stays 16B-aligned)
    float* P_lds  = sm + 24 + TC;  // 4 * HH: per-wave scaled partials

    if (tid < KK) wsh[tid] = conv_w[tid];
    __syncthreads();
    const float cb = conv_b[0];
    for (int i = tid; i < TC; i += 256) {
        float acc = cb;
#pragma unroll
        for (int k = 0; k < KK; ++k) {
            int t = t0 + i - PD + k;
            float a = (t >= 0 && t < TT) ? ax[(size_t)b * TT + t] : 0.f;
            acc += a * wsh[k];
        }
        loc_sh[i] = acc;
    }
    __syncthreads();

    // dhx slice in registers: float4 slot j, lane l -> elements (j*64+l)*4 ..+3
    const float4* dh4 = reinterpret_cast<const float4*>(dhx) + b * (HH / 4);
    float4 dh[4];
#pragma unroll
    for (int j = 0; j < 4; ++j) dh[j] = dh4[j * 64 + lane];

    const float4* e4 =
        reinterpret_cast<const float4*>(eh) + ((size_t)b * TT + t0) * (HH / 4);

    float m = -INFINITY, Z = 0.f;
    float4 P[4];
#pragma unroll
    for (int j = 0; j < 4; ++j) P[j] = make_float4(0.f, 0.f, 0.f, 0.f);

    // prefetch first row (row index within chunk: i*4 + wave)
    float4 cur[4];
    {
        const float4* rp = e4 + (size_t)wave * (HH / 4);
#pragma unroll
        for (int j = 0; j < 4; ++j) cur[j] = rp[j * 64 + lane];
    }

    for (int i = 0; i < ROWS; ++i) {
        float4 nxt[4];
        if (i + 1 < ROWS) {  // uniform branch
            const float4* rq = e4 + (size_t)((i + 1) * 4 + wave) * (HH / 4);
#pragma unroll
            for (int j = 0; j < 4; ++j) nxt[j] = rq[j * 64 + lane];
        }

        float s = 0.f;
#pragma unroll
        for (int j = 0; j < 4; ++j)
            s += cur[j].x * dh[j].x + cur[j].y * dh[j].y + cur[j].z * dh[j].z +
                 cur[j].w * dh[j].w;
#pragma unroll
        for (int off = 1; off < 64; off <<= 1) s += __shfl_xor(s, off, 64);
        s += loc_sh[i * 4 + wave];

        if (lane == 0) stash[(size_t)b * TT + t0 + i * 4 + wave] = s;

        if (s > m) {  // wave-uniform
            float sc = __expf(m - s);
            Z *= sc;
#pragma unroll
            for (int j = 0; j < 4; ++j) {
                P[j].x *= sc; P[j].y *= sc; P[j].z *= sc; P[j].w *= sc;
            }
            m = s;
        }
        float p = __expf(s - m);
        Z += p;
#pragma unroll
        for (int j = 0; j < 4; ++j) {
            P[j].x += p * cur[j].x; P[j].y += p * cur[j].y;
            P[j].z += p * cur[j].z; P[j].w += p * cur[j].w;
        }

        if (i + 1 < ROWS) {
#pragma unroll
            for (int j = 0; j < 4; ++j) cur[j] = nxt[j];
        }
    }

    // ---- combine 4 waves (2 barriers total) ----
    if (lane == 0) { mz[wave] = m; mz[4 + wave] = Z; }
    __syncthreads();
    const float mb = fmaxf(fmaxf(mz[0], mz[1]), fmaxf(mz[2], mz[3]));
    const float sc = __expf(m - mb);  // wave-uniform
    float4* Pl4 = reinterpret_cast<float4*>(P_lds);
#pragma unroll
    for (int j = 0; j < 4; ++j) {
        float4 q = P[j];
        q.x *= sc; q.y *= sc; q.z *= sc; q.w *= sc;
        Pl4[wave * 256 + j * 64 + lane] = q;
    }
    __syncthreads();
    float4 a0 = Pl4[tid], a1 = Pl4[256 + tid], a2 = Pl4[512 + tid],
           a3 = Pl4[768 + tid];
    float4 acc;
    acc.x = a0.x + a1.x + a2.x + a3.x;
    acc.y = a0.y + a1.y + a2.y + a3.y;
    acc.z = a0.z + a1.z + a2.z + a3.z;
    acc.w = a0.w + a1.w + a2.w + a3.w;
    reinterpret_cast<float4*>(part)[((size_t)b * NC + c) * 256 + tid] = acc;

    if (tid == 0) {
        float Zb = 0.f;
#pragma unroll
        for (int w = 0; w < 4; ++w) Zb += __expf(mz[w] - mb) * mz[4 + w];
        mArr[b * NC + c] = mb;
        ZArr[b * NC + c] = Zb;
    }
}

// ---------------- Merged tail: sx combine + ax_new ------------------------------
// grid (5, B): blockIdx.x<4 -> sx quarter; ==4 -> ax_new for batch b.
__global__ __launch_bounds__(256) void tail_kernel(
    const float* __restrict__ mArr, const float* __restrict__ ZArr,
    const float* __restrict__ part, const float* __restrict__ stash,
    float* __restrict__ sx, float* __restrict__ ax_new, int NC) {
    const int b = blockIdx.y;
    float mg = -INFINITY;
    for (int c = 0; c < NC; ++c) mg = fmaxf(mg, mArr[b * NC + c]);
    float Zg = 0.f;
    for (int c = 0; c < NC; ++c) Zg += __expf(mArr[b * NC + c] - mg) * ZArr[b * NC + c];

    if (blockIdx.x < 4) {
        const int h = blockIdx.x * 256 + threadIdx.x;
        float acc = 0.f;
        for (int c = 0; c < NC; ++c)
            acc += __expf(mArr[b * NC + c] - mg) * part[((size_t)b * NC + c) * HH + h];
        sx[(size_t)b * HH + h] = acc / Zg;
    } else {
        const float inv = 1.f / Zg;
        for (int j = 0; j < TT; j += 256) {
            int t = j + threadIdx.x;
            ax_new[(size_t)b * TT + t] =
                __expf(stash[(size_t)b * TT + t] - mg) * inv;
        }
    }
}

extern "C" void kernel_launch(void* const* d_in, const int* in_sizes, int n_in,
                              void* d_out, int out_size, void* d_ws, size_t ws_size,
                              hipStream_t stream) {
    const float* eh  = (const float*)d_in[0];
    const float* dhx = (const float*)d_in[1];
    const float* ax  = (const float*)d_in[2];
    const float* cw  = (const float*)d_in[3];
    const float* cb  = (const float*)d_in[4];

    float* out    = (float*)d_out;
    float* sx     = out;            // (B,1,H)
    float* ax_new = out + BB * HH;  // (B,T)

    int nc = 32;
    while (nc > 4 &&
           ((size_t)BB * TT + 2ull * BB * nc + (size_t)BB * nc * HH + 64) * 4 > ws_size)
        nc >>= 1;

    float* stash = (float*)d_ws;             // B*T
    float* mArr  = stash + (size_t)BB * TT;  // B*nc
    float* ZArr  = mArr + (size_t)BB * nc;   // B*nc
    float* part  = ZArr + (size_t)BB * nc;   // B*nc*H

    const int TC = TT / nc;
    const size_t lds_bytes = (24 + TC + 4 * HH) * sizeof(float);

    dim3 gmain(nc, BB);
    fused_main_kernel<<<gmain, 256, lds_bytes, stream>>>(eh, dhx, ax, cw, cb,
                                                         stash, mArr, ZArr, part);
    dim3 gtail(5, BB);
    tail_kernel<<<gtail, 256, 0, stream>>>(mArr, ZArr, part, stash, sx, ax_new, nc);
}